// Round 9
// baseline (600.575 us; speedup 1.0000x reference)
//
#include <hip/hip_runtime.h>
#include <stdint.h>

#define B_    4
#define S_    2048
#define DM    1024
#define NH    16
#define DH    64
#define BH    (B_ * NH)    // 64
#define MROWS (B_ * S_)    // 8192
#define LOG2E 1.4426950408889634f

typedef __attribute__((ext_vector_type(8))) short short8;
typedef __attribute__((ext_vector_type(4))) float f32x4;
typedef __attribute__((ext_vector_type(16))) float f32x16;
typedef __attribute__((ext_vector_type(4))) unsigned int u32x4;

__device__ __forceinline__ unsigned short f2bf(float f) {
  unsigned int u = __float_as_uint(f);
  u = (u + 0x7FFFu + ((u >> 16) & 1u)) >> 16;
  return (unsigned short)u;
}
// round-half-up pack (PROVEN in R4)
__device__ __forceinline__ unsigned int pack_bf16(float lo, float hi) {
  unsigned int a = (__float_as_uint(lo) + 0x8000u) >> 16;
  unsigned int b = (__float_as_uint(hi) + 0x8000u) & 0xFFFF0000u;
  return a | b;
}

__device__ __forceinline__ void gll16(const void* g, const void* l) {
  __builtin_amdgcn_global_load_lds(
      (__attribute__((address_space(1))) void*)(unsigned long long)g,
      (__attribute__((address_space(3))) void*)(unsigned int)(unsigned long long)l,
      16, 0, 0);
}

// ---------------------------------------------------------------- prep
// z in [0,3]: W[z] fp32 [k][n] -> W^T bf16 [n][k].  z in [4,7]: x -> bf16.
__global__ __launch_bounds__(256) void prep_kernel(
    const float* __restrict__ x,
    const float* __restrict__ Wq, const float* __restrict__ Wk,
    const float* __restrict__ Wv, const float* __restrict__ Wo,
    unsigned short* __restrict__ xb,
    unsigned short* __restrict__ wt_qkv, unsigned short* __restrict__ wt_o) {
  __shared__ float t[32][33];
  const int z = blockIdx.z;
  if (z >= 4) {
    size_t lb = (size_t)(z - 4) * 1024 + blockIdx.y * 32 + blockIdx.x;
    size_t i = (lb * 256 + threadIdx.x) * 8;
    float4 a = *(const float4*)(x + i);
    float4 b = *(const float4*)(x + i + 4);
    short8 o;
    o[0] = (short)f2bf(a.x); o[1] = (short)f2bf(a.y);
    o[2] = (short)f2bf(a.z); o[3] = (short)f2bf(a.w);
    o[4] = (short)f2bf(b.x); o[5] = (short)f2bf(b.y);
    o[6] = (short)f2bf(b.z); o[7] = (short)f2bf(b.w);
    *(short8*)(xb + i) = o;
    return;
  }
  const float* W = z == 0 ? Wq : z == 1 ? Wk : z == 2 ? Wv : Wo;
  unsigned short* dst = z < 3 ? wt_qkv + (size_t)z * DM * DM : wt_o;
  const int nb = blockIdx.x * 32, kb = blockIdx.y * 32;
  const int tx = threadIdx.x & 31, ty = threadIdx.x >> 5;
#pragma unroll
  for (int p = 0; p < 4; ++p) {
    int r = ty + p * 8;
    t[r][tx] = W[(size_t)(kb + r) * DM + nb + tx];
  }
  __syncthreads();
#pragma unroll
  for (int p = 0; p < 4; ++p) {
    int r = ty + p * 8;
    dst[(size_t)(nb + r) * DM + kb + tx] = f2bf(t[tx][r]);
  }
}

// V [bh][s][d] -> Vt [bh][d][s]
__global__ __launch_bounds__(256) void transpose_v_kernel(
    const unsigned short* __restrict__ V, unsigned short* __restrict__ Vt) {
  __shared__ unsigned short t[32][33];
  const int bh = blockIdx.z;
  const int sb = blockIdx.x * 32, db = blockIdx.y * 32;
  const int tx = threadIdx.x & 31, ty = threadIdx.x >> 5;
  const unsigned short* Vp = V + (size_t)bh * S_ * DH;
  unsigned short* Vtp = Vt + (size_t)bh * DH * S_;
#pragma unroll
  for (int p = 0; p < 4; ++p) {
    int r = ty + p * 8;
    t[r][tx] = Vp[(size_t)(sb + r) * DH + db + tx];
  }
  __syncthreads();
#pragma unroll
  for (int p = 0; p < 4; ++p) {
    int r = ty + p * 8;
    Vtp[(size_t)(db + r) * S_ + sb + tx] = t[tx][r];
  }
}

// ---------------------------------------------------------------- GEMM core
// 32x32x16 MFMA; layouts HW-verified (m74/m101/m89).
__device__ __forceinline__ void gemm_core(const unsigned short* __restrict__ A,
                                          const unsigned short* __restrict__ Bt,
                                          int m0, int n0,
                                          unsigned short* As, unsigned short* Bs,
                                          f32x16 (&acc)[2][2]) {
  const int tid = threadIdx.x;
  const int lane = tid & 63, wave = tid >> 6;
  const int l31 = lane & 31, half = lane >> 5;
  const int wm = (wave >> 1) * 64, wn = (wave & 1) * 64;

  for (int kk = 0; kk < DM; kk += 64) {
#pragma unroll
    for (int p = 0; p < 4; ++p) {
      int idx = p * 256 + tid;
      int row = idx >> 3, ch = idx & 7;
      int sc = (ch ^ (row & 7)) << 3;
      gll16(A  + (size_t)(m0 + row) * DM + kk + sc, As + idx * 8);
      gll16(Bt + (size_t)(n0 + row) * DM + kk + sc, Bs + idx * 8);
    }
    __syncthreads();
#pragma unroll
    for (int ks = 0; ks < 4; ++ks) {   // 4 k-steps of 16
      short8 af[2], bf[2];
#pragma unroll
      for (int mi = 0; mi < 2; ++mi) {
        int row = wm + mi * 32 + l31;
        af[mi] = *(const short8*)&As[row * 64 + (((ks * 2 + half) ^ (l31 & 7)) << 3)];
      }
#pragma unroll
      for (int nj = 0; nj < 2; ++nj) {
        int row = wn + nj * 32 + l31;
        bf[nj] = *(const short8*)&Bs[row * 64 + (((ks * 2 + half) ^ (l31 & 7)) << 3)];
      }
#pragma unroll
      for (int mi = 0; mi < 2; ++mi)
#pragma unroll
        for (int nj = 0; nj < 2; ++nj)
          acc[mi][nj] = __builtin_amdgcn_mfma_f32_32x32x16_bf16(af[mi], bf[nj], acc[mi][nj], 0, 0, 0);
    }
    __syncthreads();
  }
}

__global__ __launch_bounds__(256, 4) void gemm_qkv_kernel(
    const unsigned short* __restrict__ xb, const unsigned short* __restrict__ wt,
    const float* __restrict__ bq, const float* __restrict__ bk, const float* __restrict__ bv,
    unsigned short* __restrict__ Qb, unsigned short* __restrict__ Kb,
    unsigned short* __restrict__ Vb) {
  __shared__ unsigned short As[128 * 64];
  __shared__ unsigned short Bs[128 * 64];
  f32x16 acc[2][2] = {};
  const int m0 = blockIdx.y * 128, n0 = blockIdx.x * 128;
  gemm_core(xb, wt, m0, n0, As, Bs, acc);

  const int tid = threadIdx.x, lane = tid & 63, wave = tid >> 6;
  const int l31 = lane & 31, half = lane >> 5;
  const int wm = (wave >> 1) * 64, wn = (wave & 1) * 64;
  const int which = n0 >> 10;
  const float* bias = which == 0 ? bq : (which == 1 ? bk : bv);
  unsigned short* dst = which == 0 ? Qb : (which == 1 ? Kb : Vb);
  const float scale = (which == 0) ? 0.125f * LOG2E : 1.0f;
  const int nb = n0 - (which << 10);
#pragma unroll
  for (int nj = 0; nj < 2; ++nj) {
    int n10 = nb + wn + nj * 32 + l31;
    float bsv = bias[n10];
    int h = n10 >> 6, d = n10 & 63;
#pragma unroll
    for (int mi = 0; mi < 2; ++mi) {
#pragma unroll
      for (int reg = 0; reg < 16; ++reg) {
        int m = m0 + wm + mi * 32 + (reg & 3) + 8 * (reg >> 2) + 4 * half;
        int b = m >> 11, s = m & 2047;
        float v = (acc[mi][nj][reg] + bsv) * scale;
        dst[(((size_t)(b * NH + h)) * S_ + s) * DH + d] = f2bf(v);
      }
    }
  }
}

__global__ __launch_bounds__(256, 4) void gemm_out_kernel(
    const unsigned short* __restrict__ ctx, const unsigned short* __restrict__ wto,
    const float* __restrict__ bo, float* __restrict__ out) {
  __shared__ unsigned short As[128 * 64];
  __shared__ unsigned short Bs[128 * 64];
  f32x16 acc[2][2] = {};
  const int m0 = blockIdx.y * 128, n0 = blockIdx.x * 128;
  gemm_core(ctx, wto, m0, n0, As, Bs, acc);

  const int tid = threadIdx.x, lane = tid & 63, wave = tid >> 6;
  const int l31 = lane & 31, half = lane >> 5;
  const int wm = (wave >> 1) * 64, wn = (wave & 1) * 64;
#pragma unroll
  for (int nj = 0; nj < 2; ++nj) {
    int n = n0 + wn + nj * 32 + l31;
    float bsv = bo[n];
#pragma unroll
    for (int mi = 0; mi < 2; ++mi) {
#pragma unroll
      for (int reg = 0; reg < 16; ++reg) {
        int m = m0 + wm + mi * 32 + (reg & 3) + 8 * (reg >> 2) + 4 * half;
        out[(size_t)m * DM + n] = acc[mi][nj][reg] + bsv;
      }
    }
  }
}

// ---------------------------------------------------------------- attention
// R9: single-buffered K and V (32 KiB LDS) -> 5 blocks/CU via
// __launch_bounds__(256,5). Staging for kt+1 is issued AFTER the reads-done
// barrier; the next loop-top barrier drains it. Within-block prefetch is
// gone, but 5 co-resident blocks hide the staging latency cross-block
// (m114). All index math / swizzles / softmax / bpermute UNCHANGED from the
// validated R7 kernel.
__global__ __launch_bounds__(256, 5) void attn_kernel(
    const unsigned short* __restrict__ Qb, const unsigned short* __restrict__ Kb,
    const unsigned short* __restrict__ Vt, unsigned short* __restrict__ ctx) {
  __shared__ unsigned short Ks[128 * 64];  // 16 KiB
  __shared__ unsigned short Vs[64 * 128];  // 16 KiB

  const int tid = threadIdx.x, lane = tid & 63, wave = tid >> 6;
  const int col = lane & 15, quad = lane >> 4;
  const int bh = blockIdx.x;
  const int qt = 15 - blockIdx.y;
  const int b = bh >> 4, h = bh & 15;

  const unsigned short* Qp = Qb + ((size_t)bh * S_ + qt * 128) * DH;
  const unsigned short* Kbase = Kb + (size_t)bh * S_ * DH;
  const unsigned short* Vbase = Vt + (size_t)bh * DH * S_;

  // prologue: issue K[0] and V[0] staging; Q fragments -> registers (direct)
#pragma unroll
  for (int p = 0; p < 4; ++p) {
    int idx = p * 256 + tid;
    {
      int row = idx >> 3, ch = idx & 7;
      int sc = (ch ^ (row & 7)) << 3;
      gll16(Kbase + row * 64 + sc, Ks + idx * 8);
    }
    {
      int row = idx >> 4, ch = idx & 15;
      int sc = (ch & 8) | ((ch ^ row) & 7);
      gll16(Vbase + (size_t)row * S_ + sc * 8, Vs + idx * 8);
    }
  }
  short8 qf[2][2];  // B-operand frags: n=q=wave*32+i*16+col, k=d
#pragma unroll
  for (int i = 0; i < 2; ++i)
#pragma unroll
    for (int ksd = 0; ksd < 2; ++ksd)
      qf[i][ksd] = *(const short8*)(Qp + (wave * 32 + i * 16 + col) * 64 + ksd * 32 + quad * 8);

  f32x4 o[2][4] = {};
  f32x4 lacc[2] = {};

  const int idxA = (col + ((lane & 16) << 1)) << 2;  // src lane*4: col or col+32
  const int idxB = idxA + 64;                        // +16 lanes
  const bool hij = (lane & 32) != 0;                 // dest quads 2,3 want jt=2ks+1

  for (int kt = 0; kt <= qt; ++kt) {
    __syncthreads();  // K[kt], V[kt] resident (drains staging vmcnt)

    // S^T = K * Q^T - 8 : element (kv=jt*16+quad*4+r, q=wave*32+i*16+col)
    f32x4 sa[2][8];
#pragma unroll
    for (int jt = 0; jt < 8; ++jt) {
      int row = jt * 16 + col;
      short8 kf0 = *(const short8*)&Ks[row * 64 + ((quad ^ (row & 7)) << 3)];
      short8 kf1 = *(const short8*)&Ks[row * 64 + (((4 + quad) ^ (row & 7)) << 3)];
#pragma unroll
      for (int i = 0; i < 2; ++i) {
        f32x4 c = {-8.f, -8.f, -8.f, -8.f};
        c = __builtin_amdgcn_mfma_f32_16x16x32_bf16(kf0, qf[i][0], c, 0, 0, 0);
        c = __builtin_amdgcn_mfma_f32_16x16x32_bf16(kf1, qf[i][1], c, 0, 0, 0);
        sa[i][jt] = c;
      }
    }

    if (kt == qt) {  // causal mask on diagonal tile
#pragma unroll
      for (int i = 0; i < 2; ++i) {
        int ql = wave * 32 + i * 16 + col;
#pragma unroll
        for (int jt = 0; jt < 8; ++jt)
#pragma unroll
          for (int r = 0; r < 4; ++r)
            if (jt * 16 + quad * 4 + r > ql) sa[i][jt][r] = -__builtin_inff();
      }
    }

    // P = exp2(s); in-lane l accumulate; pack bf16 pairs (round-half-up)
    unsigned int ppk[2][8][2];
#pragma unroll
    for (int i = 0; i < 2; ++i)
#pragma unroll
      for (int jt = 0; jt < 8; ++jt) {
        f32x4 p;
#pragma unroll
        for (int c4 = 0; c4 < 4; ++c4) {
          p[c4] = __builtin_amdgcn_exp2f(sa[i][jt][c4]);
          lacc[i][c4] += p[c4];
        }
        ppk[i][jt][0] = pack_bf16(p[0], p[1]);
        ppk[i][jt][1] = pack_bf16(p[2], p[3]);
      }

    // O += P V : A-frags via ds_bpermute, FULL exec, value-select afterwards
#pragma unroll
    for (int ks = 0; ks < 4; ++ks) {
      short8 vf[4];
#pragma unroll
      for (int jo = 0; jo < 4; ++jo) {
        int row = jo * 16 + col;
        int c = ks * 4 + quad;
        int ch = (c & 8) | ((c ^ row) & 7);
        vf[jo] = *(const short8*)&Vs[row * 128 + ch * 8];
      }
#pragma unroll
      for (int i = 0; i < 2; ++i) {
        int p0 = (int)ppk[i][2 * ks][0], p1 = (int)ppk[i][2 * ks][1];
        int q0 = (int)ppk[i][2 * ks + 1][0], q1 = (int)ppk[i][2 * ks + 1][1];
        int a0 = __builtin_amdgcn_ds_bpermute(idxA, p0);
        int b0 = __builtin_amdgcn_ds_bpermute(idxA, q0);
        int a1 = __builtin_amdgcn_ds_bpermute(idxA, p1);
        int b1 = __builtin_amdgcn_ds_bpermute(idxA, q1);
        int a2 = __builtin_amdgcn_ds_bpermute(idxB, p0);
        int b2 = __builtin_amdgcn_ds_bpermute(idxB, q0);
        int a3 = __builtin_amdgcn_ds_bpermute(idxB, p1);
        int b3 = __builtin_amdgcn_ds_bpermute(idxB, q1);
        u32x4 uu;
        uu[0] = (unsigned)(hij ? b0 : a0);
        uu[1] = (unsigned)(hij ? b1 : a1);
        uu[2] = (unsigned)(hij ? b2 : a2);
        uu[3] = (unsigned)(hij ? b3 : a3);
        short8 af = __builtin_bit_cast(short8, uu);
#pragma unroll
        for (int jo = 0; jo < 4; ++jo)
          o[i][jo] = __builtin_amdgcn_mfma_f32_16x16x32_bf16(af, vf[jo], o[i][jo], 0, 0, 0);
      }
    }

    __syncthreads();  // all Ks/Vs reads done; safe to overwrite

    if (kt < qt) {    // issue K[kt+1], V[kt+1]; next loop-top barrier drains
      const unsigned short* Kp = Kbase + (size_t)(kt + 1) * 128 * DH;
      const unsigned short* Vp = Vbase + (kt + 1) * 128;
#pragma unroll
      for (int p = 0; p < 4; ++p) {
        int idx = p * 256 + tid;
        {
          int row = idx >> 3, ch = idx & 7;
          int sc = (ch ^ (row & 7)) << 3;
          gll16(Kp + row * 64 + sc, Ks + idx * 8);
        }
        {
          int row = idx >> 4, ch = idx & 15;
          int sc = (ch & 8) | ((ch ^ row) & 7);
          gll16(Vp + (size_t)row * S_ + sc * 8, Vs + idx * 8);
        }
      }
    }
  }

  // epilogue: reduce l across quads, write ctx
#pragma unroll
  for (int i = 0; i < 2; ++i) {
    float l = (lacc[i][0] + lacc[i][1]) + (lacc[i][2] + lacc[i][3]);
    l += __shfl_xor(l, 16);
    l += __shfl_xor(l, 32);
#pragma unroll
    for (int r = 0; r < 4; ++r) {
      float lr = __shfl(l, ((lane >> 4) << 2) + r);
      float inv = __builtin_amdgcn_rcpf(lr);
      int s = qt * 128 + wave * 32 + i * 16 + quad * 4 + r;
#pragma unroll
      for (int jo = 0; jo < 4; ++jo) {
        int d = jo * 16 + col;
        ctx[((size_t)(b * S_ + s)) * DM + h * DH + d] = f2bf(o[i][jo][r] * inv);
      }
    }
  }
}

// ---------------------------------------------------------------- launch
extern "C" void kernel_launch(void* const* d_in, const int* in_sizes, int n_in,
                              void* d_out, int out_size, void* d_ws, size_t ws_size,
                              hipStream_t stream) {
  (void)in_sizes; (void)n_in; (void)out_size; (void)ws_size;
  const float* x  = (const float*)d_in[0];
  const float* Wq = (const float*)d_in[1];
  const float* bq = (const float*)d_in[2];
  const float* Wk = (const float*)d_in[3];
  const float* bk = (const float*)d_in[4];
  const float* Wv = (const float*)d_in[5];
  const float* bv = (const float*)d_in[6];
  const float* Wo = (const float*)d_in[7];
  const float* bo = (const float*)d_in[8];
  float* out = (float*)d_out;

  char* ws = (char*)d_ws;
  size_t off = 0;
  auto carve = [&](size_t bytes) -> char* {
    char* p = ws + off;
    off += (bytes + 255) & ~(size_t)255;
    return p;
  };
  unsigned short* xb  = (unsigned short*)carve((size_t)MROWS * DM * 2);
  unsigned short* wtq = (unsigned short*)carve((size_t)3 * DM * DM * 2);
  unsigned short* wto = (unsigned short*)carve((size_t)DM * DM * 2);
  unsigned short* Qb  = (unsigned short*)carve((size_t)BH * S_ * DH * 2);
  unsigned short* Kb  = (unsigned short*)carve((size_t)BH * S_ * DH * 2);
  unsigned short* Vb  = (unsigned short*)carve((size_t)BH * S_ * DH * 2);
  unsigned short* Vt  = (unsigned short*)carve((size_t)BH * S_ * DH * 2);
  unsigned short* ctx = Vb;  // Vb dead after transpose_v; reuse

  prep_kernel<<<dim3(32, 32, 8), 256, 0, stream>>>(x, Wq, Wk, Wv, Wo, xb, wtq, wto);
  gemm_qkv_kernel<<<dim3(24, 64), 256, 0, stream>>>(xb, wtq, bq, bk, bv, Qb, Kb, Vb);
  transpose_v_kernel<<<dim3(64, 2, 64), 256, 0, stream>>>(Vb, Vt);
  attn_kernel<<<dim3(64, 16), 256, 0, stream>>>(Qb, Kb, Vt, ctx);
  gemm_out_kernel<<<dim3(8, 64), 256, 0, stream>>>(ctx, wto, bo, out);
}

// Round 10
// 262.368 us; speedup vs baseline: 2.2891x; 2.2891x over previous
//
#include <hip/hip_runtime.h>
#include <stdint.h>

#define B_    4
#define S_    2048
#define DM    1024
#define NH    16
#define DH    64
#define BH    (B_ * NH)    // 64
#define MROWS (B_ * S_)    // 8192
#define LOG2E 1.4426950408889634f

typedef __attribute__((ext_vector_type(8))) short short8;
typedef __attribute__((ext_vector_type(4))) float f32x4;
typedef __attribute__((ext_vector_type(16))) float f32x16;
typedef __attribute__((ext_vector_type(4))) unsigned int u32x4;

__device__ __forceinline__ unsigned short f2bf(float f) {
  unsigned int u = __float_as_uint(f);
  u = (u + 0x7FFFu + ((u >> 16) & 1u)) >> 16;
  return (unsigned short)u;
}
// round-half-up pack (PROVEN in R4)
__device__ __forceinline__ unsigned int pack_bf16(float lo, float hi) {
  unsigned int a = (__float_as_uint(lo) + 0x8000u) >> 16;
  unsigned int b = (__float_as_uint(hi) + 0x8000u) & 0xFFFF0000u;
  return a | b;
}

__device__ __forceinline__ void gll16(const void* g, const void* l) {
  __builtin_amdgcn_global_load_lds(
      (__attribute__((address_space(1))) void*)(unsigned long long)g,
      (__attribute__((address_space(3))) void*)(unsigned int)(unsigned long long)l,
      16, 0, 0);
}

// ---------------------------------------------------------------- prep
// z in [0,3]: W[z] fp32 [k][n] -> W^T bf16 [n][k].  z in [4,7]: x -> bf16.
__global__ __launch_bounds__(256) void prep_kernel(
    const float* __restrict__ x,
    const float* __restrict__ Wq, const float* __restrict__ Wk,
    const float* __restrict__ Wv, const float* __restrict__ Wo,
    unsigned short* __restrict__ xb,
    unsigned short* __restrict__ wt_qkv, unsigned short* __restrict__ wt_o) {
  __shared__ float t[32][33];
  const int z = blockIdx.z;
  if (z >= 4) {
    size_t lb = (size_t)(z - 4) * 1024 + blockIdx.y * 32 + blockIdx.x;
    size_t i = (lb * 256 + threadIdx.x) * 8;
    float4 a = *(const float4*)(x + i);
    float4 b = *(const float4*)(x + i + 4);
    short8 o;
    o[0] = (short)f2bf(a.x); o[1] = (short)f2bf(a.y);
    o[2] = (short)f2bf(a.z); o[3] = (short)f2bf(a.w);
    o[4] = (short)f2bf(b.x); o[5] = (short)f2bf(b.y);
    o[6] = (short)f2bf(b.z); o[7] = (short)f2bf(b.w);
    *(short8*)(xb + i) = o;
    return;
  }
  const float* W = z == 0 ? Wq : z == 1 ? Wk : z == 2 ? Wv : Wo;
  unsigned short* dst = z < 3 ? wt_qkv + (size_t)z * DM * DM : wt_o;
  const int nb = blockIdx.x * 32, kb = blockIdx.y * 32;
  const int tx = threadIdx.x & 31, ty = threadIdx.x >> 5;
#pragma unroll
  for (int p = 0; p < 4; ++p) {
    int r = ty + p * 8;
    t[r][tx] = W[(size_t)(kb + r) * DM + nb + tx];
  }
  __syncthreads();
#pragma unroll
  for (int p = 0; p < 4; ++p) {
    int r = ty + p * 8;
    dst[(size_t)(nb + r) * DM + kb + tx] = f2bf(t[tx][r]);
  }
}

// ---------------------------------------------------------------- GEMM core
// 32x32x16 MFMA; layouts HW-verified (m74/m101/m89).
__device__ __forceinline__ void gemm_core(const unsigned short* __restrict__ A,
                                          const unsigned short* __restrict__ Bt,
                                          int m0, int n0,
                                          unsigned short* As, unsigned short* Bs,
                                          f32x16 (&acc)[2][2]) {
  const int tid = threadIdx.x;
  const int lane = tid & 63, wave = tid >> 6;
  const int l31 = lane & 31, half = lane >> 5;
  const int wm = (wave >> 1) * 64, wn = (wave & 1) * 64;

  for (int kk = 0; kk < DM; kk += 64) {
#pragma unroll
    for (int p = 0; p < 4; ++p) {
      int idx = p * 256 + tid;
      int row = idx >> 3, ch = idx & 7;
      int sc = (ch ^ (row & 7)) << 3;
      gll16(A  + (size_t)(m0 + row) * DM + kk + sc, As + idx * 8);
      gll16(Bt + (size_t)(n0 + row) * DM + kk + sc, Bs + idx * 8);
    }
    __syncthreads();
#pragma unroll
    for (int ks = 0; ks < 4; ++ks) {   // 4 k-steps of 16
      short8 af[2], bf[2];
#pragma unroll
      for (int mi = 0; mi < 2; ++mi) {
        int row = wm + mi * 32 + l31;
        af[mi] = *(const short8*)&As[row * 64 + (((ks * 2 + half) ^ (l31 & 7)) << 3)];
      }
#pragma unroll
      for (int nj = 0; nj < 2; ++nj) {
        int row = wn + nj * 32 + l31;
        bf[nj] = *(const short8*)&Bs[row * 64 + (((ks * 2 + half) ^ (l31 & 7)) << 3)];
      }
#pragma unroll
      for (int mi = 0; mi < 2; ++mi)
#pragma unroll
        for (int nj = 0; nj < 2; ++nj)
          acc[mi][nj] = __builtin_amdgcn_mfma_f32_32x32x16_bf16(af[mi], bf[nj], acc[mi][nj], 0, 0, 0);
    }
    __syncthreads();
  }
}

// QKV projection. V is written DIRECTLY in transposed [bh][d][s] layout
// (replaces the former transpose_v kernel; epilogue index change only).
__global__ __launch_bounds__(256) void gemm_qkv_kernel(
    const unsigned short* __restrict__ xb, const unsigned short* __restrict__ wt,
    const float* __restrict__ bq, const float* __restrict__ bk, const float* __restrict__ bv,
    unsigned short* __restrict__ Qb, unsigned short* __restrict__ Kb,
    unsigned short* __restrict__ Vt) {
  __shared__ unsigned short As[128 * 64];
  __shared__ unsigned short Bs[128 * 64];
  f32x16 acc[2][2] = {};
  const int m0 = blockIdx.y * 128, n0 = blockIdx.x * 128;
  gemm_core(xb, wt, m0, n0, As, Bs, acc);

  const int tid = threadIdx.x, lane = tid & 63, wave = tid >> 6;
  const int l31 = lane & 31, half = lane >> 5;
  const int wm = (wave >> 1) * 64, wn = (wave & 1) * 64;
  const int which = n0 >> 10;
  const int nb = n0 - (which << 10);
  if (which == 2) {
    // V -> Vt[bh][d][s]
#pragma unroll
    for (int nj = 0; nj < 2; ++nj) {
      int n10 = nb + wn + nj * 32 + l31;
      float bsv = bv[n10];
      int h = n10 >> 6, d = n10 & 63;
#pragma unroll
      for (int mi = 0; mi < 2; ++mi) {
#pragma unroll
        for (int reg = 0; reg < 16; ++reg) {
          int m = m0 + wm + mi * 32 + (reg & 3) + 8 * (reg >> 2) + 4 * half;
          int b = m >> 11, s = m & 2047;
          Vt[(((size_t)(b * NH + h)) * DH + d) * S_ + s] = f2bf(acc[mi][nj][reg] + bsv);
        }
      }
    }
    return;
  }
  const float* bias = which == 0 ? bq : bk;
  unsigned short* dst = which == 0 ? Qb : Kb;
  const float scale = (which == 0) ? 0.125f * LOG2E : 1.0f;
#pragma unroll
  for (int nj = 0; nj < 2; ++nj) {
    int n10 = nb + wn + nj * 32 + l31;
    float bsv = bias[n10];
    int h = n10 >> 6, d = n10 & 63;
#pragma unroll
    for (int mi = 0; mi < 2; ++mi) {
#pragma unroll
      for (int reg = 0; reg < 16; ++reg) {
        int m = m0 + wm + mi * 32 + (reg & 3) + 8 * (reg >> 2) + 4 * half;
        int b = m >> 11, s = m & 2047;
        float v = (acc[mi][nj][reg] + bsv) * scale;
        dst[(((size_t)(b * NH + h)) * S_ + s) * DH + d] = f2bf(v);
      }
    }
  }
}

__global__ __launch_bounds__(256) void gemm_out_kernel(
    const unsigned short* __restrict__ ctx, const unsigned short* __restrict__ wto,
    const float* __restrict__ bo, float* __restrict__ out) {
  __shared__ unsigned short As[128 * 64];
  __shared__ unsigned short Bs[128 * 64];
  f32x16 acc[2][2] = {};
  const int m0 = blockIdx.y * 128, n0 = blockIdx.x * 128;
  gemm_core(ctx, wto, m0, n0, As, Bs, acc);

  const int tid = threadIdx.x, lane = tid & 63, wave = tid >> 6;
  const int l31 = lane & 31, half = lane >> 5;
  const int wm = (wave >> 1) * 64, wn = (wave & 1) * 64;
#pragma unroll
  for (int nj = 0; nj < 2; ++nj) {
    int n = n0 + wn + nj * 32 + l31;
    float bsv = bo[n];
#pragma unroll
    for (int mi = 0; mi < 2; ++mi) {
#pragma unroll
      for (int reg = 0; reg < 16; ++reg) {
        int m = m0 + wm + mi * 32 + (reg & 3) + 8 * (reg >> 2) + 4 * half;
        out[(size_t)m * DM + n] = acc[mi][nj][reg] + bsv;
      }
    }
  }
}

// ---------------------------------------------------------------- attention
// EXACT R8 revert (validated, 80 µs): S^T = K*Q^T, static-max softmax
// P=2^(s-8) (-8 folded into MFMA C-init), Q direct-to-registers, K dbuf,
// V prefetch, ds_bpermute C->A transform (full-exec gathers + value select).
// DO NOT add min-waves launch bounds: R9's (256,5) capped the unified
// VGPR+AGPR file -> scratch spills -> 1.5 GB HBM traffic, 5x regression.
__global__ __launch_bounds__(256, 3) void attn_kernel(
    const unsigned short* __restrict__ Qb, const unsigned short* __restrict__ Kb,
    const unsigned short* __restrict__ Vt, unsigned short* __restrict__ ctx) {
  __shared__ unsigned short Ks[2][128 * 64];  // 32 KiB (dbuf)
  __shared__ unsigned short Vs[64 * 128];     // 16 KiB

  const int tid = threadIdx.x, lane = tid & 63, wave = tid >> 6;
  const int col = lane & 15, quad = lane >> 4;
  const int bh = blockIdx.x;
  const int qt = 15 - blockIdx.y;
  const int b = bh >> 4, h = bh & 15;

  const unsigned short* Qp = Qb + ((size_t)bh * S_ + qt * 128) * DH;
  const unsigned short* Kbase = Kb + (size_t)bh * S_ * DH;
  const unsigned short* Vbase = Vt + (size_t)bh * DH * S_;

  // prologue: K tile 0 -> Ks[0] (async); Q fragments -> registers (direct)
#pragma unroll
  for (int p = 0; p < 4; ++p) {
    int idx = p * 256 + tid;
    int row = idx >> 3, ch = idx & 7;
    int sc = (ch ^ (row & 7)) << 3;
    gll16(Kbase + row * 64 + sc, &Ks[0][0] + idx * 8);
  }
  short8 qf[2][2];  // B-operand frags: n=q=wave*32+i*16+col, k=d
#pragma unroll
  for (int i = 0; i < 2; ++i)
#pragma unroll
    for (int ksd = 0; ksd < 2; ++ksd)
      qf[i][ksd] = *(const short8*)(Qp + (wave * 32 + i * 16 + col) * 64 + ksd * 32 + quad * 8);
  __syncthreads();  // Ks[0] resident

  f32x4 o[2][4] = {};
  f32x4 lacc[2] = {};

  const int idxA = (col + ((lane & 16) << 1)) << 2;  // src lane*4: col or col+32
  const int idxB = idxA + 64;                        // +16 lanes
  const bool hij = (lane & 32) != 0;                 // dest quads 2,3 want jt=2ks+1

  for (int kt = 0; kt <= qt; ++kt) {
    const int cur = kt & 1;
    // issue V[kt] and K[kt+1] NOW; they fly during S + softmax
    const unsigned short* Vp = Vbase + kt * 128;
#pragma unroll
    for (int p = 0; p < 4; ++p) {
      int idx = p * 256 + tid;
      int row = idx >> 4, ch = idx & 15;
      int sc = (ch & 8) | ((ch ^ row) & 7);
      gll16(Vp + (size_t)row * S_ + sc * 8, Vs + idx * 8);
    }
    if (kt < qt) {
      const unsigned short* Kp = Kbase + (size_t)(kt + 1) * 128 * DH;
#pragma unroll
      for (int p = 0; p < 4; ++p) {
        int idx = p * 256 + tid;
        int row = idx >> 3, ch = idx & 7;
        int sc = (ch ^ (row & 7)) << 3;
        gll16(Kp + row * 64 + sc, &Ks[cur ^ 1][0] + idx * 8);
      }
    }

    // S^T = K * Q^T - 8 : element (kv=jt*16+quad*4+r, q=wave*32+i*16+col)
    f32x4 sa[2][8];
#pragma unroll
    for (int jt = 0; jt < 8; ++jt) {
      int row = jt * 16 + col;
      short8 kf0 = *(const short8*)&Ks[cur][row * 64 + ((quad ^ (row & 7)) << 3)];
      short8 kf1 = *(const short8*)&Ks[cur][row * 64 + (((4 + quad) ^ (row & 7)) << 3)];
#pragma unroll
      for (int i = 0; i < 2; ++i) {
        f32x4 c = {-8.f, -8.f, -8.f, -8.f};
        c = __builtin_amdgcn_mfma_f32_16x16x32_bf16(kf0, qf[i][0], c, 0, 0, 0);
        c = __builtin_amdgcn_mfma_f32_16x16x32_bf16(kf1, qf[i][1], c, 0, 0, 0);
        sa[i][jt] = c;
      }
    }

    if (kt == qt) {  // causal mask on diagonal tile
#pragma unroll
      for (int i = 0; i < 2; ++i) {
        int ql = wave * 32 + i * 16 + col;
#pragma unroll
        for (int jt = 0; jt < 8; ++jt)
#pragma unroll
          for (int r = 0; r < 4; ++r)
            if (jt * 16 + quad * 4 + r > ql) sa[i][jt][r] = -__builtin_inff();
      }
    }

    // P = exp2(s); in-lane l accumulate; pack bf16 pairs (round-half-up)
    unsigned int ppk[2][8][2];
#pragma unroll
    for (int i = 0; i < 2; ++i)
#pragma unroll
      for (int jt = 0; jt < 8; ++jt) {
        f32x4 p;
#pragma unroll
        for (int c4 = 0; c4 < 4; ++c4) {
          p[c4] = __builtin_amdgcn_exp2f(sa[i][jt][c4]);
          lacc[i][c4] += p[c4];
        }
        ppk[i][jt][0] = pack_bf16(p[0], p[1]);
        ppk[i][jt][1] = pack_bf16(p[2], p[3]);
      }

    __syncthreads();  // V[kt] (and K[kt+1]) now resident

    // O += P V : A-frags via ds_bpermute, FULL exec, value-select afterwards
#pragma unroll
    for (int ks = 0; ks < 4; ++ks) {
      short8 vf[4];
#pragma unroll
      for (int jo = 0; jo < 4; ++jo) {
        int row = jo * 16 + col;
        int c = ks * 4 + quad;
        int ch = (c & 8) | ((c ^ row) & 7);
        vf[jo] = *(const short8*)&Vs[row * 128 + ch * 8];
      }
#pragma unroll
      for (int i = 0; i < 2; ++i) {
        int p0 = (int)ppk[i][2 * ks][0], p1 = (int)ppk[i][2 * ks][1];
        int q0 = (int)ppk[i][2 * ks + 1][0], q1 = (int)ppk[i][2 * ks + 1][1];
        int a0 = __builtin_amdgcn_ds_bpermute(idxA, p0);
        int b0 = __builtin_amdgcn_ds_bpermute(idxA, q0);
        int a1 = __builtin_amdgcn_ds_bpermute(idxA, p1);
        int b1 = __builtin_amdgcn_ds_bpermute(idxA, q1);
        int a2 = __builtin_amdgcn_ds_bpermute(idxB, p0);
        int b2 = __builtin_amdgcn_ds_bpermute(idxB, q0);
        int a3 = __builtin_amdgcn_ds_bpermute(idxB, p1);
        int b3 = __builtin_amdgcn_ds_bpermute(idxB, q1);
        u32x4 uu;
        uu[0] = (unsigned)(hij ? b0 : a0);
        uu[1] = (unsigned)(hij ? b1 : a1);
        uu[2] = (unsigned)(hij ? b2 : a2);
        uu[3] = (unsigned)(hij ? b3 : a3);
        short8 af = __builtin_bit_cast(short8, uu);
#pragma unroll
        for (int jo = 0; jo < 4; ++jo)
          o[i][jo] = __builtin_amdgcn_mfma_f32_16x16x32_bf16(af, vf[jo], o[i][jo], 0, 0, 0);
      }
    }
    __syncthreads();  // Vs WAR before next iteration's V issue
  }

  // epilogue: reduce l across quads, write ctx
#pragma unroll
  for (int i = 0; i < 2; ++i) {
    float l = (lacc[i][0] + lacc[i][1]) + (lacc[i][2] + lacc[i][3]);
    l += __shfl_xor(l, 16);
    l += __shfl_xor(l, 32);
#pragma unroll
    for (int r = 0; r < 4; ++r) {
      float lr = __shfl(l, ((lane >> 4) << 2) + r);
      float inv = __builtin_amdgcn_rcpf(lr);
      int s = qt * 128 + wave * 32 + i * 16 + quad * 4 + r;
#pragma unroll
      for (int jo = 0; jo < 4; ++jo) {
        int d = jo * 16 + col;
        ctx[((size_t)(b * S_ + s)) * DM + h * DH + d] = f2bf(o[i][jo][r] * inv);
      }
    }
  }
}

// ---------------------------------------------------------------- launch
extern "C" void kernel_launch(void* const* d_in, const int* in_sizes, int n_in,
                              void* d_out, int out_size, void* d_ws, size_t ws_size,
                              hipStream_t stream) {
  (void)in_sizes; (void)n_in; (void)out_size; (void)ws_size;
  const float* x  = (const float*)d_in[0];
  const float* Wq = (const float*)d_in[1];
  const float* bq = (const float*)d_in[2];
  const float* Wk = (const float*)d_in[3];
  const float* bk = (const float*)d_in[4];
  const float* Wv = (const float*)d_in[5];
  const float* bv = (const float*)d_in[6];
  const float* Wo = (const float*)d_in[7];
  const float* bo = (const float*)d_in[8];
  float* out = (float*)d_out;

  char* ws = (char*)d_ws;
  size_t off = 0;
  auto carve = [&](size_t bytes) -> char* {
    char* p = ws + off;
    off += (bytes + 255) & ~(size_t)255;
    return p;
  };
  unsigned short* xb  = (unsigned short*)carve((size_t)MROWS * DM * 2);
  unsigned short* wtq = (unsigned short*)carve((size_t)3 * DM * DM * 2);
  unsigned short* wto = (unsigned short*)carve((size_t)DM * DM * 2);
  unsigned short* Qb  = (unsigned short*)carve((size_t)BH * S_ * DH * 2);
  unsigned short* Kb  = (unsigned short*)carve((size_t)BH * S_ * DH * 2);
  unsigned short* Vt  = (unsigned short*)carve((size_t)BH * S_ * DH * 2);
  unsigned short* ctx = (unsigned short*)carve((size_t)BH * S_ * DH * 2);

  prep_kernel<<<dim3(32, 32, 8), 256, 0, stream>>>(x, Wq, Wk, Wv, Wo, xb, wtq, wto);
  gemm_qkv_kernel<<<dim3(24, 64), 256, 0, stream>>>(xb, wtq, bq, bk, bv, Qb, Kb, Vt);
  attn_kernel<<<dim3(64, 16), 256, 0, stream>>>(Qb, Kb, Vt, ctx);
  gemm_out_kernel<<<dim3(8, 64), 256, 0, stream>>>(ctx, wto, bo, out);
}